// Round 6
// baseline (264.704 us; speedup 1.0000x reference)
//
#include <hip/hip_runtime.h>
#include <stdint.h>

#define NH 12
#define HD 64
#define NB 4
#define SEQ 1024
#define CDIM 768
#define MTOT (NB*SEQ)
#define MC   (MTOT*CDIM)      /* 3145728 */
#define LC   (SEQ*CDIM)       /* 786432  */
#define WSZ  (CDIM*CDIM)      /* 589824  */
#define LST  104              /* attn P LDS row stride (shorts) */
#define EST  136              /* epilogue LDS row stride (shorts), z<2 */
#define VST  72               /* transposed-V epilogue row stride (64 tok + 8 pad) */
#define L2E  1.44269504f
#define BHSZ (SEQ*HD)         /* 65536 shorts per (b,h) */

typedef __attribute__((ext_vector_type(4))) float f32x4;
typedef __attribute__((ext_vector_type(8))) __bf16 bf16x8;
typedef __attribute__((ext_vector_type(8))) short short8;
typedef __attribute__((ext_vector_type(4))) unsigned short ushort4v;
typedef unsigned short u16;

static __device__ __forceinline__ f32x4 mfma16(short8 a, short8 b, f32x4 c) {
  return __builtin_amdgcn_mfma_f32_16x16x32_bf16(
      __builtin_bit_cast(bf16x8, a), __builtin_bit_cast(bf16x8, b), c, 0, 0, 0);
}
static __device__ __forceinline__ u16 f2bf(float f) {
  unsigned u = __float_as_uint(f);
  u += 0x7FFFu + ((u >> 16) & 1u);
  return (u16)(u >> 16);
}
static __device__ __forceinline__ float bf2f(u16 h) {
  return __uint_as_float(((unsigned)h) << 16);
}
static __device__ __forceinline__ void lds_load16(const void* g, void* l) {
  __builtin_amdgcn_global_load_lds(
      (const __attribute__((address_space(1))) void*)g,
      (__attribute__((address_space(3))) void*)l, 16, 0, 0);
}

// ---- fused prep: Xq/Xk/Xv bf16 tokens + all weights/bias -> bf16 ----
#define PREP_BLKS (MC / 4 / 256)
#define CONV_N4   ((4 * WSZ + CDIM) / 4)
#define CONV_BLKS ((CONV_N4 + 255) / 256)
__global__ __launch_bounds__(256) void prep_all(
    const float* __restrict__ xp, const float* __restrict__ qp,
    const float* __restrict__ kp, const float* __restrict__ Wq,
    const float* __restrict__ Wk, const float* __restrict__ Wv,
    const float* __restrict__ Wp, const float* __restrict__ bp,
    u16* __restrict__ Xq, u16* __restrict__ Xk, u16* __restrict__ Xv,
    u16* __restrict__ Wb) {
  int bid = blockIdx.x;
  if (bid < PREP_BLKS) {
    int i4 = bid * 256 + threadIdx.x;
    int a4 = i4 % (LC / 4);
    f32x4 xx = ((const f32x4*)xp)[i4];
    f32x4 qq = ((const f32x4*)qp)[a4];
    f32x4 kk = ((const f32x4*)kp)[a4];
    ushort4v oq, ok, ov;
#pragma unroll
    for (int j = 0; j < 4; j++) {
      oq[j] = f2bf(xx[j] + qq[j]);
      ok[j] = f2bf(xx[j] + kk[j]);
      ov[j] = f2bf(xx[j]);
    }
    ((ushort4v*)Xq)[i4] = oq;
    ((ushort4v*)Xk)[i4] = ok;
    ((ushort4v*)Xv)[i4] = ov;
  } else {
    int i4 = (bid - PREP_BLKS) * 256 + threadIdx.x;
    if (i4 >= CONV_N4) return;
    int sel = i4 / (WSZ / 4);
    int off = i4 - sel * (WSZ / 4);
    const float* src = sel == 0 ? Wq : sel == 1 ? Wk : sel == 2 ? Wv
                     : sel == 3 ? Wp : bp;
    f32x4 v = ((const f32x4*)src)[off];
    ushort4v o;
#pragma unroll
    for (int j = 0; j < 4; j++) o[j] = f2bf(v[j]);
    ((ushort4v*)Wb)[i4] = o;
  }
}

// ---- 64x128 (K=768) bf16 GEMM core, BK=64 as two interleaved BK=32 halves.
static __device__ __forceinline__ void gemm_core64(
    const u16* __restrict__ Ab, const u16* __restrict__ Wb,
    short* As, short* Bs, f32x4 acc[2][4]) {
  const int t = threadIdx.x;
  const int lane = t & 63, w = t >> 6, quad = lane >> 4, l16 = lane & 15;
  const int wm = (w >> 1) * 32, wn = (w & 1) * 64;
  const int row4 = t >> 2, chunk = (t & 3) * 8;
  for (int k0 = 0; k0 < CDIM; k0 += 64) {
#pragma unroll
    for (int hh = 0; hh < 2; hh++) {
      const u16* ga = Ab + row4 * CDIM + k0 + hh * 32 + chunk;
      const u16* gb = Wb + row4 * CDIM + k0 + hh * 32 + chunk;
      lds_load16(ga,             (char*)As + hh * 4096 + t * 16);
      lds_load16(gb,             (char*)Bs + hh * 8192 + t * 16);
      lds_load16(gb + 64 * CDIM, (char*)Bs + hh * 8192 + 4096 + t * 16);
    }
    __syncthreads();
#pragma unroll
    for (int hh = 0; hh < 2; hh++) {
      const short* Ah = As + hh * 2048;
      const short* Bh = Bs + hh * 4096;
      short8 af[2], bw[4];
#pragma unroll
      for (int i = 0; i < 2; i++)
        af[i] = *(const short8*)(Ah + (wm + i * 16 + l16) * 32 + quad * 8);
#pragma unroll
      for (int j = 0; j < 4; j++)
        bw[j] = *(const short8*)(Bh + (wn + j * 16 + l16) * 32 + quad * 8);
#pragma unroll
      for (int i = 0; i < 2; i++)
#pragma unroll
        for (int j = 0; j < 4; j++)
          acc[i][j] = mfma16(af[i], bw[j], acc[i][j]);
    }
    __syncthreads();
  }
}

// ---- QKV projections (64x128 tiles). z=0:Q (pre-scaled 0.125, row-major)
//      z=1:K fragment layout   z=2:V fragment layout (VST=72 stride, in-bounds)
__global__ __launch_bounds__(256) void gemm_qkv(
    const u16* __restrict__ Xq, const u16* __restrict__ Xk, const u16* __restrict__ Xv,
    const u16* __restrict__ Wq, const u16* __restrict__ Wk, const u16* __restrict__ Wv,
    u16* __restrict__ Q, u16* __restrict__ K, u16* __restrict__ Vt) {
  __shared__ __align__(16) short S[12288];   // 24.6KB: As(8KB)+Bs(16KB)
  short* As = S;
  short* Bs = S + 4096;
  const int z = blockIdx.z;
  const int m0 = blockIdx.y * 64, n0 = blockIdx.x * 128;
  const u16* A = (z == 0 ? Xq : z == 1 ? Xk : Xv) + m0 * CDIM;
  const u16* W = (z == 0 ? Wq : z == 1 ? Wk : Wv) + n0 * CDIM;
  f32x4 acc[2][4];
#pragma unroll
  for (int i = 0; i < 2; i++)
#pragma unroll
    for (int j = 0; j < 4; j++) acc[i][j] = 0.f;
  gemm_core64(A, W, As, Bs, acc);

  const int t = threadIdx.x, lane = t & 63, w = t >> 6;
  const int quad = lane >> 4, l16 = lane & 15;
  const int wm = (w >> 1) * 32, wn = (w & 1) * 64;
  const float qs = (z == 0) ? 0.125f : 1.0f;

#pragma unroll
  for (int i = 0; i < 2; i++)
#pragma unroll
    for (int j = 0; j < 4; j++)
#pragma unroll
      for (int r = 0; r < 4; r++) {
        int mr = wm + i * 16 + quad * 4 + r;
        int nc = wn + j * 16 + l16;
        if (z < 2) S[mr * EST + nc] = (short)f2bf(acc[i][j][r] * qs);
        else       S[nc * VST + mr] = (short)f2bf(acc[i][j][r]);
      }
  __syncthreads();

  const int row = t >> 3, ch = t & 7;
  const int b = m0 >> 10, lbase = m0 & 1023;
  if (z == 0) {
#pragma unroll
    for (int cp = 0; cp < 2; cp++) {
      int h = (n0 >> 6) + cp;
#pragma unroll
      for (int rp = 0; rp < 2; rp++) {
        int mr = row + rp * 32;
        short8 v = *(const short8*)(S + mr * EST + cp * 64 + ch * 8);
        *(short8*)(Q + ((((size_t)(b * NH + h)) << 10) + lbase + mr) * HD + ch * 8) = v;
      }
    }
  } else if (z == 1) {
#pragma unroll
    for (int cp = 0; cp < 2; cp++) {
      int h = (n0 >> 6) + cp;
      u16* Kp = K + (size_t)(b * NH + h) * BHSZ;
#pragma unroll
      for (int rp = 0; rp < 2; rp++) {
        int mr = row + rp * 32;
        int tok = lbase + mr;
        short8 v = *(const short8*)(S + mr * EST + cp * 64 + ch * 8);
        *(short8*)(Kp + (((tok >> 4) * 8 + ch) * 16 + (tok & 15)) * 8) = v;
      }
    }
  } else {
#pragma unroll
    for (int rp = 0; rp < 4; rp++) {
      int rn = row + rp * 32;            // local d-row of transposed tile (n-dim)
      int h = (n0 + rn) >> 6, d = rn & 63;
      u16* Vp = Vt + (size_t)(b * NH + h) * BHSZ;
      int jv = d >> 4, ld16 = d & 15;
      int tok = lbase + ch * 8;          // m-dim: 64 tokens in this block
      short8 v = *(const short8*)(S + rn * VST + ch * 8);
      *(short8*)(Vp + ((((tok >> 6) * 4 + jv) * 8 + ((tok >> 3) & 7)) * 16 + ld16) * 8) = v;
    }
  }
}

// ---- flash attention: 768 blocks (best structure), barrier-free, with
// DEEP PREFETCH: pos at distance 2 (double-buffered pfA/pfB via explicit
// 2-unroll -> static reg indexing), kb reload right after QK consumption,
// setprio(1) around MFMA clusters. Targets the exposed L3 latency of the
// pos stream (per-XCD pos slice 6MB > 4MB L2), which was the invariant
// across all three 55-59us attn variants.
__global__ __launch_bounds__(256, 3) void attn(
    const u16* __restrict__ Q, const u16* __restrict__ Kf, const u16* __restrict__ Vf,
    const float* __restrict__ pos, u16* __restrict__ O) {
  __shared__ __align__(16) short Ps[4 * 16 * LST];
  const int t = threadIdx.x, lane = t & 63, w = t >> 6;
  const int quad = lane >> 4, l16 = lane & 15;

  // XCD-clustered decode (round-robin lid%8 -> XCD; permutation only)
  const int lid = blockIdx.x;
  const int k8 = lid & 7, m = lid >> 3;
  const int g = k8 * 24 + (m >> 2), b = m & 3;
  const int h = g >> 4, qt = g & 15;
  const int bh = b * NH + h;
  const int q0 = qt * 64 + w * 16;

  const u16* Kg = Kf + (size_t)bh * BHSZ;
  const u16* Vg = Vf + (size_t)bh * BHSZ;
  const float* Pg = pos + (size_t)(h * SEQ + q0) * SEQ;
  short* Pw = Ps + w * 16 * LST;
  const int fo = quad * 128 + l16 * 8;   // fragment offset (shorts)

  const u16* Qg = Q + ((size_t)bh * SEQ + q0) * HD;
  const short8 qa0 = *(const short8*)(Qg + l16 * HD + quad * 8);
  const short8 qa1 = *(const short8*)(Qg + l16 * HD + 32 + quad * 8);

  f32x4 o[4];
  float lrow[4];
#pragma unroll
  for (int j = 0; j < 4; j++) o[j] = 0.f;
#pragma unroll
  for (int r = 0; r < 4; r++) lrow[r] = 0.f;

  short8 kb0[4], kb1[4];
  float pfA[16], pfB[16];
#pragma unroll
  for (int j = 0; j < 4; j++) {
    kb0[j] = *(const short8*)(Kg + j * 1024 + fo);
    kb1[j] = *(const short8*)(Kg + j * 1024 + 512 + fo);
  }
#pragma unroll
  for (int j = 0; j < 4; j++)
#pragma unroll
    for (int r = 0; r < 4; r++) {
      pfA[j * 4 + r] = Pg[(quad * 4 + r) * SEQ + j * 16 + l16] * L2E;
      pfB[j * 4 + r] = Pg[(quad * 4 + r) * SEQ + 64 + j * 16 + l16] * L2E;
    }

  // one tile: vb issue -> QK -> kb reload(t+1) -> softmax(PF) -> PF reload(t+2)
  //           -> P LDS round-trip -> PV
  auto tile_body = [&](int kt, float (&PF)[16]) {
    const int kbase = kt * 4096;
    short8 vb0[4], vb1[4];
#pragma unroll
    for (int j = 0; j < 4; j++) {
      vb0[j] = *(const short8*)(Vg + kbase + j * 1024 + fo);
      vb1[j] = *(const short8*)(Vg + kbase + j * 1024 + 512 + fo);
    }
    f32x4 s[4];
    __builtin_amdgcn_s_setprio(1);
#pragma unroll
    for (int j = 0; j < 4; j++) {
      f32x4 zz = 0.f;
      s[j] = mfma16(qa1, kb1[j], mfma16(qa0, kb0[j], zz));
    }
    __builtin_amdgcn_s_setprio(0);
    // reload kb for tile kt+1 (clamped; redundant at the tail, harmless)
    {
      const int nt = kt + 1 < 16 ? kt + 1 : 15;
      const int nb = nt * 4096;
#pragma unroll
      for (int j = 0; j < 4; j++) {
        kb0[j] = *(const short8*)(Kg + nb + j * 1024 + fo);
        kb1[j] = *(const short8*)(Kg + nb + j * 1024 + 512 + fo);
      }
    }
    // softmax: P = exp2(s*log2e + pos*log2e); lrow accumulates the SAME
    // bf16-truncated values stored to LDS (bias cancels in the normalize).
#pragma unroll
    for (int j = 0; j < 4; j++)
#pragma unroll
      for (int r = 0; r < 4; r++) {
        float e = __builtin_amdgcn_exp2f(fmaf(s[j][r], L2E, PF[j * 4 + r]));
        unsigned bits = __float_as_uint(e);
        Pw[(quad * 4 + r) * LST + j * 16 + l16] = (short)(bits >> 16);
        lrow[r] += __uint_as_float(bits & 0xFFFF0000u);
      }
    // reload this PF buffer for tile kt+2 (distance-2 pos prefetch)
    {
      const int nt = kt + 2 < 16 ? kt + 2 : 15;
      const float* pg = Pg + nt * 64;
#pragma unroll
      for (int j = 0; j < 4; j++)
#pragma unroll
        for (int r = 0; r < 4; r++)
          PF[j * 4 + r] = pg[(quad * 4 + r) * SEQ + j * 16 + l16] * L2E;
    }
    // P fragments (same-wave LDS round trip)
    const short8 pa0 = *(const short8*)(Pw + l16 * LST + quad * 8);
    const short8 pa1 = *(const short8*)(Pw + l16 * LST + 32 + quad * 8);
    __builtin_amdgcn_s_setprio(1);
#pragma unroll
    for (int j = 0; j < 4; j++)
      o[j] = mfma16(pa1, vb1[j], mfma16(pa0, vb0[j], o[j]));
    __builtin_amdgcn_s_setprio(0);
  };

#pragma unroll 1
  for (int kp = 0; kp < 8; ++kp) {
    tile_body(kp * 2,     pfA);
    tile_body(kp * 2 + 1, pfB);
  }

#pragma unroll
  for (int off = 1; off < 16; off <<= 1)
#pragma unroll
    for (int r = 0; r < 4; r++) lrow[r] += __shfl_xor(lrow[r], off);

  u16* Og = O + ((size_t)b * SEQ + q0) * CDIM + h * HD;
  float inv[4];
#pragma unroll
  for (int r = 0; r < 4; r++) inv[r] = 1.0f / lrow[r];
#pragma unroll
  for (int j = 0; j < 4; j++)
#pragma unroll
    for (int r = 0; r < 4; r++)
      Og[(quad * 4 + r) * CDIM + j * 16 + l16] = f2bf(o[j][r] * inv[r]);
}

// ---- output projection + bias, FP32 output (64x128 tiles) ----
__global__ __launch_bounds__(256) void gemm_proj(
    const u16* __restrict__ Oin, const u16* __restrict__ Wp,
    const u16* __restrict__ bp, float* __restrict__ out) {
  __shared__ __align__(16) short S[12288];
  const int m0 = blockIdx.y * 64, n0 = blockIdx.x * 128;
  f32x4 acc[2][4];
#pragma unroll
  for (int i = 0; i < 2; i++)
#pragma unroll
    for (int j = 0; j < 4; j++) acc[i][j] = 0.f;
  gemm_core64(Oin + m0 * CDIM, Wp + n0 * CDIM, S, S + 4096, acc);

  const int t = threadIdx.x, lane = t & 63, w = t >> 6;
  const int quad = lane >> 4, l16 = lane & 15;
  const int wm = (w >> 1) * 32, wn = (w & 1) * 64;
#pragma unroll
  for (int i = 0; i < 2; i++) {
    int mrow = m0 + wm + i * 16 + quad * 4;
#pragma unroll
    for (int j = 0; j < 4; j++) {
      int n = n0 + wn + j * 16 + l16;
      float bias = bf2f(bp[n]);
#pragma unroll
      for (int r = 0; r < 4; r++)
        out[(mrow + r) * CDIM + n] = acc[i][j][r] + bias;
    }
  }
}

extern "C" void kernel_launch(void* const* d_in, const int* in_sizes, int n_in,
                              void* d_out, int out_size, void* d_ws, size_t ws_size,
                              hipStream_t stream) {
  (void)in_sizes; (void)n_in; (void)out_size;
  const size_t OFF_XQ = 0, OFF_XK = (size_t)MC, OFF_XV = 2ull * MC,
               OFF_Q = 3ull * MC, OFF_K = 4ull * MC, OFF_VT = 5ull * MC,
               OFF_W = 6ull * MC, TOT = OFF_W + 4ull * WSZ + 1024;
  const size_t NEED = 2 * TOT;
  if (ws_size < NEED) return;

  u16* ws = (u16*)d_ws;
  u16 *Xq = ws + OFF_XQ, *Xk = ws + OFF_XK, *Xv = ws + OFF_XV;
  u16 *Qb = ws + OFF_Q, *Kb = ws + OFF_K, *Vt = ws + OFF_VT;
  u16 *Wb = ws + OFF_W;
  u16 *Wqb = Wb, *Wkb = Wb + WSZ, *Wvb = Wb + 2ull * WSZ,
      *Wpb = Wb + 3ull * WSZ, *bpb = Wb + 4ull * WSZ;
  u16* Ob = Xq;

  prep_all<<<PREP_BLKS + CONV_BLKS, 256, 0, stream>>>(
      (const float*)d_in[0], (const float*)d_in[1], (const float*)d_in[2],
      (const float*)d_in[4], (const float*)d_in[5], (const float*)d_in[6],
      (const float*)d_in[7], (const float*)d_in[8], Xq, Xk, Xv, Wb);
  gemm_qkv<<<dim3(6, 64, 3), 256, 0, stream>>>(Xq, Xk, Xv, Wqb, Wkb, Wvb,
                                               Qb, Kb, Vt);
  attn<<<dim3(768), 256, 0, stream>>>(Qb, Kb, Vt, (const float*)d_in[3], Ob);
  gemm_proj<<<dim3(6, 64), 256, 0, stream>>>(Ob, Wpb, bpb, (float*)d_out);
}

// Round 7
// 220.989 us; speedup vs baseline: 1.1978x; 1.1978x over previous
//
#include <hip/hip_runtime.h>
#include <stdint.h>

#define NH 12
#define HD 64
#define NB 4
#define SEQ 1024
#define CDIM 768
#define MTOT (NB*SEQ)
#define MC   (MTOT*CDIM)      /* 3145728 */
#define LC   (SEQ*CDIM)       /* 786432  */
#define WSZ  (CDIM*CDIM)      /* 589824  */
#define LST  104              /* attn P LDS row stride (shorts) */
#define EST  136              /* epilogue LDS row stride (shorts), z<2 */
#define VST  72               /* transposed-V epilogue row stride (64 tok + 8 pad) */
#define L2E  1.44269504f
#define BHSZ (SEQ*HD)         /* 65536 shorts per (b,h) */

typedef __attribute__((ext_vector_type(4))) float f32x4;
typedef __attribute__((ext_vector_type(8))) __bf16 bf16x8;
typedef __attribute__((ext_vector_type(8))) short short8;
typedef __attribute__((ext_vector_type(4))) unsigned short ushort4v;
typedef unsigned short u16;

static __device__ __forceinline__ f32x4 mfma16(short8 a, short8 b, f32x4 c) {
  return __builtin_amdgcn_mfma_f32_16x16x32_bf16(
      __builtin_bit_cast(bf16x8, a), __builtin_bit_cast(bf16x8, b), c, 0, 0, 0);
}
static __device__ __forceinline__ u16 f2bf(float f) {
  unsigned u = __float_as_uint(f);
  u += 0x7FFFu + ((u >> 16) & 1u);
  return (u16)(u >> 16);
}
static __device__ __forceinline__ float bf2f(u16 h) {
  return __uint_as_float(((unsigned)h) << 16);
}
static __device__ __forceinline__ void lds_load16(const void* g, void* l) {
  __builtin_amdgcn_global_load_lds(
      (const __attribute__((address_space(1))) void*)g,
      (__attribute__((address_space(3))) void*)l, 16, 0, 0);
}

// ---- fused prep: Xq/Xk/Xv bf16 tokens + all weights/bias -> bf16 ----
#define PREP_BLKS (MC / 4 / 256)
#define CONV_N4   ((4 * WSZ + CDIM) / 4)
#define CONV_BLKS ((CONV_N4 + 255) / 256)
__global__ __launch_bounds__(256) void prep_all(
    const float* __restrict__ xp, const float* __restrict__ qp,
    const float* __restrict__ kp, const float* __restrict__ Wq,
    const float* __restrict__ Wk, const float* __restrict__ Wv,
    const float* __restrict__ Wp, const float* __restrict__ bp,
    u16* __restrict__ Xq, u16* __restrict__ Xk, u16* __restrict__ Xv,
    u16* __restrict__ Wb) {
  int bid = blockIdx.x;
  if (bid < PREP_BLKS) {
    int i4 = bid * 256 + threadIdx.x;
    int a4 = i4 % (LC / 4);
    f32x4 xx = ((const f32x4*)xp)[i4];
    f32x4 qq = ((const f32x4*)qp)[a4];
    f32x4 kk = ((const f32x4*)kp)[a4];
    ushort4v oq, ok, ov;
#pragma unroll
    for (int j = 0; j < 4; j++) {
      oq[j] = f2bf(xx[j] + qq[j]);
      ok[j] = f2bf(xx[j] + kk[j]);
      ov[j] = f2bf(xx[j]);
    }
    ((ushort4v*)Xq)[i4] = oq;
    ((ushort4v*)Xk)[i4] = ok;
    ((ushort4v*)Xv)[i4] = ov;
  } else {
    int i4 = (bid - PREP_BLKS) * 256 + threadIdx.x;
    if (i4 >= CONV_N4) return;
    int sel = i4 / (WSZ / 4);
    int off = i4 - sel * (WSZ / 4);
    const float* src = sel == 0 ? Wq : sel == 1 ? Wk : sel == 2 ? Wv
                     : sel == 3 ? Wp : bp;
    f32x4 v = ((const f32x4*)src)[off];
    ushort4v o;
#pragma unroll
    for (int j = 0; j < 4; j++) o[j] = f2bf(v[j]);
    ((ushort4v*)Wb)[i4] = o;
  }
}

// ---- 64x128 (K=768) bf16 GEMM core, BK=64 as two interleaved BK=32 halves.
static __device__ __forceinline__ void gemm_core64(
    const u16* __restrict__ Ab, const u16* __restrict__ Wb,
    short* As, short* Bs, f32x4 acc[2][4]) {
  const int t = threadIdx.x;
  const int lane = t & 63, w = t >> 6, quad = lane >> 4, l16 = lane & 15;
  const int wm = (w >> 1) * 32, wn = (w & 1) * 64;
  const int row4 = t >> 2, chunk = (t & 3) * 8;
  for (int k0 = 0; k0 < CDIM; k0 += 64) {
#pragma unroll
    for (int hh = 0; hh < 2; hh++) {
      const u16* ga = Ab + row4 * CDIM + k0 + hh * 32 + chunk;
      const u16* gb = Wb + row4 * CDIM + k0 + hh * 32 + chunk;
      lds_load16(ga,             (char*)As + hh * 4096 + t * 16);
      lds_load16(gb,             (char*)Bs + hh * 8192 + t * 16);
      lds_load16(gb + 64 * CDIM, (char*)Bs + hh * 8192 + 4096 + t * 16);
    }
    __syncthreads();
#pragma unroll
    for (int hh = 0; hh < 2; hh++) {
      const short* Ah = As + hh * 2048;
      const short* Bh = Bs + hh * 4096;
      short8 af[2], bw[4];
#pragma unroll
      for (int i = 0; i < 2; i++)
        af[i] = *(const short8*)(Ah + (wm + i * 16 + l16) * 32 + quad * 8);
#pragma unroll
      for (int j = 0; j < 4; j++)
        bw[j] = *(const short8*)(Bh + (wn + j * 16 + l16) * 32 + quad * 8);
#pragma unroll
      for (int i = 0; i < 2; i++)
#pragma unroll
        for (int j = 0; j < 4; j++)
          acc[i][j] = mfma16(af[i], bw[j], acc[i][j]);
    }
    __syncthreads();
  }
}

// ---- QKV projections (64x128 tiles). z=0:Q (pre-scaled 0.125, row-major)
//      z=1:K fragment layout   z=2:V fragment layout (VST=72 stride, in-bounds)
__global__ __launch_bounds__(256) void gemm_qkv(
    const u16* __restrict__ Xq, const u16* __restrict__ Xk, const u16* __restrict__ Xv,
    const u16* __restrict__ Wq, const u16* __restrict__ Wk, const u16* __restrict__ Wv,
    u16* __restrict__ Q, u16* __restrict__ K, u16* __restrict__ Vt) {
  __shared__ __align__(16) short S[12288];   // 24.6KB: As(8KB)+Bs(16KB)
  short* As = S;
  short* Bs = S + 4096;
  const int z = blockIdx.z;
  const int m0 = blockIdx.y * 64, n0 = blockIdx.x * 128;
  const u16* A = (z == 0 ? Xq : z == 1 ? Xk : Xv) + m0 * CDIM;
  const u16* W = (z == 0 ? Wq : z == 1 ? Wk : Wv) + n0 * CDIM;
  f32x4 acc[2][4];
#pragma unroll
  for (int i = 0; i < 2; i++)
#pragma unroll
    for (int j = 0; j < 4; j++) acc[i][j] = 0.f;
  gemm_core64(A, W, As, Bs, acc);

  const int t = threadIdx.x, lane = t & 63, w = t >> 6;
  const int quad = lane >> 4, l16 = lane & 15;
  const int wm = (w >> 1) * 32, wn = (w & 1) * 64;
  const float qs = (z == 0) ? 0.125f : 1.0f;

#pragma unroll
  for (int i = 0; i < 2; i++)
#pragma unroll
    for (int j = 0; j < 4; j++)
#pragma unroll
      for (int r = 0; r < 4; r++) {
        int mr = wm + i * 16 + quad * 4 + r;
        int nc = wn + j * 16 + l16;
        if (z < 2) S[mr * EST + nc] = (short)f2bf(acc[i][j][r] * qs);
        else       S[nc * VST + mr] = (short)f2bf(acc[i][j][r]);
      }
  __syncthreads();

  const int row = t >> 3, ch = t & 7;
  const int b = m0 >> 10, lbase = m0 & 1023;
  if (z == 0) {
#pragma unroll
    for (int cp = 0; cp < 2; cp++) {
      int h = (n0 >> 6) + cp;
#pragma unroll
      for (int rp = 0; rp < 2; rp++) {
        int mr = row + rp * 32;
        short8 v = *(const short8*)(S + mr * EST + cp * 64 + ch * 8);
        *(short8*)(Q + ((((size_t)(b * NH + h)) << 10) + lbase + mr) * HD + ch * 8) = v;
      }
    }
  } else if (z == 1) {
#pragma unroll
    for (int cp = 0; cp < 2; cp++) {
      int h = (n0 >> 6) + cp;
      u16* Kp = K + (size_t)(b * NH + h) * BHSZ;
#pragma unroll
      for (int rp = 0; rp < 2; rp++) {
        int mr = row + rp * 32;
        int tok = lbase + mr;
        short8 v = *(const short8*)(S + mr * EST + cp * 64 + ch * 8);
        *(short8*)(Kp + (((tok >> 4) * 8 + ch) * 16 + (tok & 15)) * 8) = v;
      }
    }
  } else {
#pragma unroll
    for (int rp = 0; rp < 4; rp++) {
      int rn = row + rp * 32;            // local d-row of transposed tile (n-dim)
      int h = (n0 + rn) >> 6, d = rn & 63;
      u16* Vp = Vt + (size_t)(b * NH + h) * BHSZ;
      int jv = d >> 4, ld16 = d & 15;
      int tok = lbase + ch * 8;          // m-dim: 64 tokens in this block
      short8 v = *(const short8*)(S + rn * VST + ch * 8);
      *(short8*)(Vp + ((((tok >> 6) * 4 + jv) * 8 + ((tok >> 3) & 7)) * 16 + ld16) * 8) = v;
    }
  }
}

// ---- flash attention: round-0 structure (768 blocks, barrier-free) + T15
// deferred-PV pipeline: tile kt's PV runs during tile kt+1's front.
// vb double-buffered (E/O), P-LDS double regions (E/O), kb ON-DEMAND
// (transient regs, L1-shared across the block's 4 waves), pos prefetch
// distance-1 single-buffered. All macro-based: no lambdas, no address-taken
// arrays (round-5 scratch lesson). Target: hide the P write->read gap and
// vb latency under a full tile of independent work.
__global__ __launch_bounds__(256, 3) void attn(
    const u16* __restrict__ Q, const u16* __restrict__ Kf, const u16* __restrict__ Vf,
    const float* __restrict__ pos, u16* __restrict__ O) {
  __shared__ __align__(16) short Ps[8 * 16 * LST];   // 2 regions per wave
  const int t = threadIdx.x, lane = t & 63, w = t >> 6;
  const int quad = lane >> 4, l16 = lane & 15;

  // XCD-clustered decode (round-robin lid%8 -> XCD; permutation only)
  const int lid = blockIdx.x;
  const int k8 = lid & 7, m = lid >> 3;
  const int g = k8 * 24 + (m >> 2), b = m & 3;
  const int h = g >> 4, qt = g & 15;
  const int bh = b * NH + h;
  const int q0 = qt * 64 + w * 16;

  const u16* Kg = Kf + (size_t)bh * BHSZ;
  const u16* Vg = Vf + (size_t)bh * BHSZ;
  const float* Pg = pos + (size_t)(h * SEQ + q0) * SEQ;
  short* PwE = Ps + w * 2 * 16 * LST;
  short* PwO = PwE + 16 * LST;
  const int fo = quad * 128 + l16 * 8;   // fragment offset (shorts)

  const u16* Qg = Q + ((size_t)bh * SEQ + q0) * HD;
  const short8 qa0 = *(const short8*)(Qg + l16 * HD + quad * 8);
  const short8 qa1 = *(const short8*)(Qg + l16 * HD + 32 + quad * 8);

  f32x4 o[4];
  float lrow[4];
#pragma unroll
  for (int j = 0; j < 4; j++) o[j] = 0.f;
#pragma unroll
  for (int r = 0; r < 4; r++) lrow[r] = 0.f;

  short8 vbE0[4], vbE1[4], vbO0[4], vbO1[4];
  float pf[16];
#pragma unroll
  for (int j = 0; j < 4; j++)
#pragma unroll
    for (int r = 0; r < 4; r++)
      pf[j * 4 + r] = Pg[(quad * 4 + r) * SEQ + j * 16 + l16] * L2E;

// FRONT(kt): kb on-demand -> vb issue -> QK -> softmax -> pos prefetch (kt+1).
// kb issued BEFORE vb so the QK's vmcnt wait doesn't also drain the vb loads.
#define FRONT(KT, VB0, VB1, PWC)                                              \
  do {                                                                        \
    const int kbase_ = (KT) * 4096;                                           \
    short8 kb0_[4], kb1_[4];                                                  \
    _Pragma("unroll")                                                         \
    for (int j = 0; j < 4; j++) {                                             \
      kb0_[j] = *(const short8*)(Kg + kbase_ + j * 1024 + fo);                \
      kb1_[j] = *(const short8*)(Kg + kbase_ + j * 1024 + 512 + fo);          \
    }                                                                         \
    _Pragma("unroll")                                                         \
    for (int j = 0; j < 4; j++) {                                             \
      VB0[j] = *(const short8*)(Vg + kbase_ + j * 1024 + fo);                 \
      VB1[j] = *(const short8*)(Vg + kbase_ + j * 1024 + 512 + fo);           \
    }                                                                         \
    f32x4 s_[4];                                                              \
    _Pragma("unroll")                                                         \
    for (int j = 0; j < 4; j++) {                                             \
      f32x4 zz = 0.f;                                                         \
      s_[j] = mfma16(qa1, kb1_[j], mfma16(qa0, kb0_[j], zz));                 \
    }                                                                         \
    _Pragma("unroll")                                                         \
    for (int j = 0; j < 4; j++)                                               \
      _Pragma("unroll")                                                       \
      for (int r = 0; r < 4; r++) {                                           \
        float e = __builtin_amdgcn_exp2f(fmaf(s_[j][r], L2E, pf[j * 4 + r])); \
        unsigned bits = __float_as_uint(e);                                   \
        PWC[(quad * 4 + r) * LST + j * 16 + l16] = (short)(bits >> 16);       \
        lrow[r] += __uint_as_float(bits & 0xFFFF0000u);                       \
      }                                                                       \
    {                                                                         \
      const int nt_ = (KT) + 1 < 16 ? (KT) + 1 : 15;                          \
      const float* pg_ = Pg + nt_ * 64;                                       \
      _Pragma("unroll")                                                       \
      for (int j = 0; j < 4; j++)                                             \
        _Pragma("unroll")                                                     \
        for (int r = 0; r < 4; r++)                                           \
          pf[j * 4 + r] = pg_[(quad * 4 + r) * SEQ + j * 16 + l16] * L2E;     \
    }                                                                         \
  } while (0)

#define PVSTEP(VB0, VB1, PWP)                                                 \
  do {                                                                        \
    const short8 pa0_ = *(const short8*)(PWP + l16 * LST + quad * 8);         \
    const short8 pa1_ = *(const short8*)(PWP + l16 * LST + 32 + quad * 8);    \
    _Pragma("unroll")                                                         \
    for (int j = 0; j < 4; j++)                                               \
      o[j] = mfma16(pa1_, VB1[j], mfma16(pa0_, VB0[j], o[j]));                \
  } while (0)

  FRONT(0, vbE0, vbE1, PwE);
#pragma unroll 1
  for (int kp = 0; kp < 7; ++kp) {
    FRONT(2 * kp + 1, vbO0, vbO1, PwO);
    PVSTEP(vbE0, vbE1, PwE);           // PV for tile 2kp
    FRONT(2 * kp + 2, vbE0, vbE1, PwE);
    PVSTEP(vbO0, vbO1, PwO);           // PV for tile 2kp+1
  }
  FRONT(15, vbO0, vbO1, PwO);
  PVSTEP(vbE0, vbE1, PwE);             // PV for tile 14
  PVSTEP(vbO0, vbO1, PwO);             // PV for tile 15

#undef FRONT
#undef PVSTEP

#pragma unroll
  for (int off = 1; off < 16; off <<= 1)
#pragma unroll
    for (int r = 0; r < 4; r++) lrow[r] += __shfl_xor(lrow[r], off);

  u16* Og = O + ((size_t)b * SEQ + q0) * CDIM + h * HD;
  float inv[4];
#pragma unroll
  for (int r = 0; r < 4; r++) inv[r] = 1.0f / lrow[r];
#pragma unroll
  for (int j = 0; j < 4; j++)
#pragma unroll
    for (int r = 0; r < 4; r++)
      Og[(quad * 4 + r) * CDIM + j * 16 + l16] = f2bf(o[j][r] * inv[r]);
}

// ---- output projection + bias, FP32 output (64x128 tiles) ----
__global__ __launch_bounds__(256) void gemm_proj(
    const u16* __restrict__ Oin, const u16* __restrict__ Wp,
    const u16* __restrict__ bp, float* __restrict__ out) {
  __shared__ __align__(16) short S[12288];
  const int m0 = blockIdx.y * 64, n0 = blockIdx.x * 128;
  f32x4 acc[2][4];
#pragma unroll
  for (int i = 0; i < 2; i++)
#pragma unroll
    for (int j = 0; j < 4; j++) acc[i][j] = 0.f;
  gemm_core64(Oin + m0 * CDIM, Wp + n0 * CDIM, S, S + 4096, acc);

  const int t = threadIdx.x, lane = t & 63, w = t >> 6;
  const int quad = lane >> 4, l16 = lane & 15;
  const int wm = (w >> 1) * 32, wn = (w & 1) * 64;
#pragma unroll
  for (int i = 0; i < 2; i++) {
    int mrow = m0 + wm + i * 16 + quad * 4;
#pragma unroll
    for (int j = 0; j < 4; j++) {
      int n = n0 + wn + j * 16 + l16;
      float bias = bf2f(bp[n]);
#pragma unroll
      for (int r = 0; r < 4; r++)
        out[(mrow + r) * CDIM + n] = acc[i][j][r] + bias;
    }
  }
}

extern "C" void kernel_launch(void* const* d_in, const int* in_sizes, int n_in,
                              void* d_out, int out_size, void* d_ws, size_t ws_size,
                              hipStream_t stream) {
  (void)in_sizes; (void)n_in; (void)out_size;
  const size_t OFF_XQ = 0, OFF_XK = (size_t)MC, OFF_XV = 2ull * MC,
               OFF_Q = 3ull * MC, OFF_K = 4ull * MC, OFF_VT = 5ull * MC,
               OFF_W = 6ull * MC, TOT = OFF_W + 4ull * WSZ + 1024;
  const size_t NEED = 2 * TOT;
  if (ws_size < NEED) return;

  u16* ws = (u16*)d_ws;
  u16 *Xq = ws + OFF_XQ, *Xk = ws + OFF_XK, *Xv = ws + OFF_XV;
  u16 *Qb = ws + OFF_Q, *Kb = ws + OFF_K, *Vt = ws + OFF_VT;
  u16 *Wb = ws + OFF_W;
  u16 *Wqb = Wb, *Wkb = Wb + WSZ, *Wvb = Wb + 2ull * WSZ,
      *Wpb = Wb + 3ull * WSZ, *bpb = Wb + 4ull * WSZ;
  u16* Ob = Xq;

  prep_all<<<PREP_BLKS + CONV_BLKS, 256, 0, stream>>>(
      (const float*)d_in[0], (const float*)d_in[1], (const float*)d_in[2],
      (const float*)d_in[4], (const float*)d_in[5], (const float*)d_in[6],
      (const float*)d_in[7], (const float*)d_in[8], Xq, Xk, Xv, Wb);
  gemm_qkv<<<dim3(6, 64, 3), 256, 0, stream>>>(Xq, Xk, Xv, Wqb, Wkb, Wvb,
                                               Qb, Kb, Vt);
  attn<<<dim3(768), 256, 0, stream>>>(Qb, Kb, Vt, (const float*)d_in[3], Ob);
  gemm_proj<<<dim3(6, 64), 256, 0, stream>>>(Ob, Wpb, bpb, (float*)d_out);
}

// Round 8
// 208.937 us; speedup vs baseline: 1.2669x; 1.0577x over previous
//
#include <hip/hip_runtime.h>
#include <stdint.h>

#define NH 12
#define HD 64
#define NB 4
#define SEQ 1024
#define CDIM 768
#define MTOT (NB*SEQ)
#define MC   (MTOT*CDIM)      /* 3145728 */
#define LC   (SEQ*CDIM)       /* 786432  */
#define WSZ  (CDIM*CDIM)      /* 589824  */
#define LST  104              /* attn P LDS row stride (shorts) */
#define EST  136              /* epilogue LDS row stride (shorts), z<2 */
#define VST  72               /* transposed-V epilogue row stride (64 tok + 8 pad) */
#define L2E  1.44269504f
#define BHSZ (SEQ*HD)         /* 65536 shorts per (b,h) */

typedef __attribute__((ext_vector_type(4))) float f32x4;
typedef __attribute__((ext_vector_type(8))) __bf16 bf16x8;
typedef __attribute__((ext_vector_type(8))) short short8;
typedef __attribute__((ext_vector_type(4))) unsigned short ushort4v;
typedef unsigned short u16;

static __device__ __forceinline__ f32x4 mfma16(short8 a, short8 b, f32x4 c) {
  return __builtin_amdgcn_mfma_f32_16x16x32_bf16(
      __builtin_bit_cast(bf16x8, a), __builtin_bit_cast(bf16x8, b), c, 0, 0, 0);
}
static __device__ __forceinline__ u16 f2bf(float f) {
  unsigned u = __float_as_uint(f);
  u += 0x7FFFu + ((u >> 16) & 1u);
  return (u16)(u >> 16);
}
static __device__ __forceinline__ float bf2f(u16 h) {
  return __uint_as_float(((unsigned)h) << 16);
}
static __device__ __forceinline__ void lds_load16(const void* g, void* l) {
  __builtin_amdgcn_global_load_lds(
      (const __attribute__((address_space(1))) void*)g,
      (__attribute__((address_space(3))) void*)l, 16, 0, 0);
}

// ---- fused prep: Xq/Xk/Xv bf16 tokens + all weights/bias -> bf16 ----
#define PREP_BLKS (MC / 4 / 256)
#define CONV_N4   ((4 * WSZ + CDIM) / 4)
#define CONV_BLKS ((CONV_N4 + 255) / 256)
__global__ __launch_bounds__(256) void prep_all(
    const float* __restrict__ xp, const float* __restrict__ qp,
    const float* __restrict__ kp, const float* __restrict__ Wq,
    const float* __restrict__ Wk, const float* __restrict__ Wv,
    const float* __restrict__ Wp, const float* __restrict__ bp,
    u16* __restrict__ Xq, u16* __restrict__ Xk, u16* __restrict__ Xv,
    u16* __restrict__ Wb) {
  int bid = blockIdx.x;
  if (bid < PREP_BLKS) {
    int i4 = bid * 256 + threadIdx.x;
    int a4 = i4 % (LC / 4);
    f32x4 xx = ((const f32x4*)xp)[i4];
    f32x4 qq = ((const f32x4*)qp)[a4];
    f32x4 kk = ((const f32x4*)kp)[a4];
    ushort4v oq, ok, ov;
#pragma unroll
    for (int j = 0; j < 4; j++) {
      oq[j] = f2bf(xx[j] + qq[j]);
      ok[j] = f2bf(xx[j] + kk[j]);
      ov[j] = f2bf(xx[j]);
    }
    ((ushort4v*)Xq)[i4] = oq;
    ((ushort4v*)Xk)[i4] = ok;
    ((ushort4v*)Xv)[i4] = ov;
  } else {
    int i4 = (bid - PREP_BLKS) * 256 + threadIdx.x;
    if (i4 >= CONV_N4) return;
    int sel = i4 / (WSZ / 4);
    int off = i4 - sel * (WSZ / 4);
    const float* src = sel == 0 ? Wq : sel == 1 ? Wk : sel == 2 ? Wv
                     : sel == 3 ? Wp : bp;
    f32x4 v = ((const f32x4*)src)[off];
    ushort4v o;
#pragma unroll
    for (int j = 0; j < 4; j++) o[j] = f2bf(v[j]);
    ((ushort4v*)Wb)[i4] = o;
  }
}

// ---- 64x128 (K=768) bf16 GEMM core, BK=64 as two interleaved BK=32 halves.
static __device__ __forceinline__ void gemm_core64(
    const u16* __restrict__ Ab, const u16* __restrict__ Wb,
    short* As, short* Bs, f32x4 acc[2][4]) {
  const int t = threadIdx.x;
  const int lane = t & 63, w = t >> 6, quad = lane >> 4, l16 = lane & 15;
  const int wm = (w >> 1) * 32, wn = (w & 1) * 64;
  const int row4 = t >> 2, chunk = (t & 3) * 8;
  for (int k0 = 0; k0 < CDIM; k0 += 64) {
#pragma unroll
    for (int hh = 0; hh < 2; hh++) {
      const u16* ga = Ab + row4 * CDIM + k0 + hh * 32 + chunk;
      const u16* gb = Wb + row4 * CDIM + k0 + hh * 32 + chunk;
      lds_load16(ga,             (char*)As + hh * 4096 + t * 16);
      lds_load16(gb,             (char*)Bs + hh * 8192 + t * 16);
      lds_load16(gb + 64 * CDIM, (char*)Bs + hh * 8192 + 4096 + t * 16);
    }
    __syncthreads();
#pragma unroll
    for (int hh = 0; hh < 2; hh++) {
      const short* Ah = As + hh * 2048;
      const short* Bh = Bs + hh * 4096;
      short8 af[2], bw[4];
#pragma unroll
      for (int i = 0; i < 2; i++)
        af[i] = *(const short8*)(Ah + (wm + i * 16 + l16) * 32 + quad * 8);
#pragma unroll
      for (int j = 0; j < 4; j++)
        bw[j] = *(const short8*)(Bh + (wn + j * 16 + l16) * 32 + quad * 8);
#pragma unroll
      for (int i = 0; i < 2; i++)
#pragma unroll
        for (int j = 0; j < 4; j++)
          acc[i][j] = mfma16(af[i], bw[j], acc[i][j]);
    }
    __syncthreads();
  }
}

// ---- QKV projections (64x128 tiles). z=0:Q (pre-scaled 0.125, row-major)
//      z=1:K fragment layout   z=2:V fragment layout (VST=72 stride, in-bounds)
__global__ __launch_bounds__(256) void gemm_qkv(
    const u16* __restrict__ Xq, const u16* __restrict__ Xk, const u16* __restrict__ Xv,
    const u16* __restrict__ Wq, const u16* __restrict__ Wk, const u16* __restrict__ Wv,
    u16* __restrict__ Q, u16* __restrict__ K, u16* __restrict__ Vt) {
  __shared__ __align__(16) short S[12288];   // 24.6KB: As(8KB)+Bs(16KB)
  short* As = S;
  short* Bs = S + 4096;
  const int z = blockIdx.z;
  const int m0 = blockIdx.y * 64, n0 = blockIdx.x * 128;
  const u16* A = (z == 0 ? Xq : z == 1 ? Xk : Xv) + m0 * CDIM;
  const u16* W = (z == 0 ? Wq : z == 1 ? Wk : Wv) + n0 * CDIM;
  f32x4 acc[2][4];
#pragma unroll
  for (int i = 0; i < 2; i++)
#pragma unroll
    for (int j = 0; j < 4; j++) acc[i][j] = 0.f;
  gemm_core64(A, W, As, Bs, acc);

  const int t = threadIdx.x, lane = t & 63, w = t >> 6;
  const int quad = lane >> 4, l16 = lane & 15;
  const int wm = (w >> 1) * 32, wn = (w & 1) * 64;
  const float qs = (z == 0) ? 0.125f : 1.0f;

#pragma unroll
  for (int i = 0; i < 2; i++)
#pragma unroll
    for (int j = 0; j < 4; j++)
#pragma unroll
      for (int r = 0; r < 4; r++) {
        int mr = wm + i * 16 + quad * 4 + r;
        int nc = wn + j * 16 + l16;
        if (z < 2) S[mr * EST + nc] = (short)f2bf(acc[i][j][r] * qs);
        else       S[nc * VST + mr] = (short)f2bf(acc[i][j][r]);
      }
  __syncthreads();

  const int row = t >> 3, ch = t & 7;
  const int b = m0 >> 10, lbase = m0 & 1023;
  if (z == 0) {
#pragma unroll
    for (int cp = 0; cp < 2; cp++) {
      int h = (n0 >> 6) + cp;
#pragma unroll
      for (int rp = 0; rp < 2; rp++) {
        int mr = row + rp * 32;
        short8 v = *(const short8*)(S + mr * EST + cp * 64 + ch * 8);
        *(short8*)(Q + ((((size_t)(b * NH + h)) << 10) + lbase + mr) * HD + ch * 8) = v;
      }
    }
  } else if (z == 1) {
#pragma unroll
    for (int cp = 0; cp < 2; cp++) {
      int h = (n0 >> 6) + cp;
      u16* Kp = K + (size_t)(b * NH + h) * BHSZ;
#pragma unroll
      for (int rp = 0; rp < 2; rp++) {
        int mr = row + rp * 32;
        int tok = lbase + mr;
        short8 v = *(const short8*)(S + mr * EST + cp * 64 + ch * 8);
        *(short8*)(Kp + (((tok >> 4) * 8 + ch) * 16 + (tok & 15)) * 8) = v;
      }
    }
  } else {
#pragma unroll
    for (int rp = 0; rp < 4; rp++) {
      int rn = row + rp * 32;            // local d-row of transposed tile (n-dim)
      int h = (n0 + rn) >> 6, d = rn & 63;
      u16* Vp = Vt + (size_t)(b * NH + h) * BHSZ;
      int jv = d >> 4, ld16 = d & 15;
      int tok = lbase + ch * 8;          // m-dim: 64 tokens in this block
      short8 v = *(const short8*)(S + rn * VST + ch * 8);
      *(short8*)(Vp + ((((tok >> 6) * 4 + jv) * 8 + ((tok >> 3) & 7)) * 16 + ld16) * 8) = v;
    }
  }
}

// ---- flash attention: EXACT round-0 structure (proven 55.2us).
// Barrier-free, LDS only for P. K/V direct from global in fragment layout
// (1KiB coalesced wave loads, L1-shared across the block's 4 waves);
// kb+pos prefetched 1 tile ahead; vb issued at iteration top.
__global__ __launch_bounds__(256, 3) void attn(
    const u16* __restrict__ Q, const u16* __restrict__ Kf, const u16* __restrict__ Vf,
    const float* __restrict__ pos, u16* __restrict__ O) {
  __shared__ __align__(16) short Ps[4 * 16 * LST];
  const int t = threadIdx.x, lane = t & 63, w = t >> 6;
  const int quad = lane >> 4, l16 = lane & 15;

  // XCD-clustered decode (round-robin lid%8 -> XCD; permutation only)
  const int lid = blockIdx.x;
  const int k8 = lid & 7, m = lid >> 3;
  const int g = k8 * 24 + (m >> 2), b = m & 3;
  const int h = g >> 4, qt = g & 15;
  const int bh = b * NH + h;
  const int q0 = qt * 64 + w * 16;

  const u16* Kg = Kf + (size_t)bh * BHSZ;
  const u16* Vg = Vf + (size_t)bh * BHSZ;
  const float* Pg = pos + (size_t)(h * SEQ + q0) * SEQ;
  short* Pw = Ps + w * 16 * LST;
  const int fo = quad * 128 + l16 * 8;   // fragment offset (shorts)

  const u16* Qg = Q + ((size_t)bh * SEQ + q0) * HD;
  const short8 qa0 = *(const short8*)(Qg + l16 * HD + quad * 8);
  const short8 qa1 = *(const short8*)(Qg + l16 * HD + 32 + quad * 8);

  f32x4 o[4];
  float lrow[4];
#pragma unroll
  for (int j = 0; j < 4; j++) o[j] = 0.f;
#pragma unroll
  for (int r = 0; r < 4; r++) lrow[r] = 0.f;

  short8 kb0[4], kb1[4];
  float pf[16];
#pragma unroll
  for (int j = 0; j < 4; j++) {
    kb0[j] = *(const short8*)(Kg + j * 1024 + fo);
    kb1[j] = *(const short8*)(Kg + j * 1024 + 512 + fo);
  }
#pragma unroll
  for (int j = 0; j < 4; j++)
#pragma unroll
    for (int r = 0; r < 4; r++)
      pf[j * 4 + r] = Pg[(quad * 4 + r) * SEQ + j * 16 + l16] * L2E;

#pragma unroll 1
  for (int kt = 0; kt < 16; ++kt) {
    const int kbase = kt * 4096;
    // issue V fragment loads for this tile (consumed after softmax)
    short8 vb0[4], vb1[4];
#pragma unroll
    for (int j = 0; j < 4; j++) {
      vb0[j] = *(const short8*)(Vg + kbase + j * 1024 + fo);
      vb1[j] = *(const short8*)(Vg + kbase + j * 1024 + 512 + fo);
    }
    // QK^T (kb prefetched last iteration)
    f32x4 s[4];
#pragma unroll
    for (int j = 0; j < 4; j++) {
      f32x4 zz = 0.f;
      s[j] = mfma16(qa1, kb1[j], mfma16(qa0, kb0[j], zz));
    }
    // P = exp2(s*log2e + pos*log2e) — no-max softmax; lrow accumulates the
    // SAME bf16-truncated values stored to LDS (bias cancels in normalize).
#pragma unroll
    for (int j = 0; j < 4; j++)
#pragma unroll
      for (int r = 0; r < 4; r++) {
        float e = __builtin_amdgcn_exp2f(fmaf(s[j][r], L2E, pf[j * 4 + r]));
        unsigned bits = __float_as_uint(e);
        Pw[(quad * 4 + r) * LST + j * 16 + l16] = (short)(bits >> 16);
        lrow[r] += __uint_as_float(bits & 0xFFFF0000u);
      }
    // prefetch next tile's K fragments + pos (covered by PV + next QK^T)
    if (kt < 15) {
      const int nb = kbase + 4096;
#pragma unroll
      for (int j = 0; j < 4; j++) {
        kb0[j] = *(const short8*)(Kg + nb + j * 1024 + fo);
        kb1[j] = *(const short8*)(Kg + nb + j * 1024 + 512 + fo);
      }
      const float* pg = Pg + (kt + 1) * 64;
#pragma unroll
      for (int j = 0; j < 4; j++)
#pragma unroll
        for (int r = 0; r < 4; r++)
          pf[j * 4 + r] = pg[(quad * 4 + r) * SEQ + j * 16 + l16] * L2E;
    }
    // P fragments (same-wave LDS round trip; compiler inserts lgkmcnt)
    const short8 pa0 = *(const short8*)(Pw + l16 * LST + quad * 8);
    const short8 pa1 = *(const short8*)(Pw + l16 * LST + 32 + quad * 8);
    // PV
#pragma unroll
    for (int j = 0; j < 4; j++)
      o[j] = mfma16(pa1, vb1[j], mfma16(pa0, vb0[j], o[j]));
  }

#pragma unroll
  for (int off = 1; off < 16; off <<= 1)
#pragma unroll
    for (int r = 0; r < 4; r++) lrow[r] += __shfl_xor(lrow[r], off);

  u16* Og = O + ((size_t)b * SEQ + q0) * CDIM + h * HD;
  float inv[4];
#pragma unroll
  for (int r = 0; r < 4; r++) inv[r] = 1.0f / lrow[r];
#pragma unroll
  for (int j = 0; j < 4; j++)
#pragma unroll
    for (int r = 0; r < 4; r++)
      Og[(quad * 4 + r) * CDIM + j * 16 + l16] = f2bf(o[j][r] * inv[r]);
}

// ---- output projection + bias, FP32 output. 64x64 tiles: grid 12x64=768
// blocks = 3/CU (was 384 = 1.5/CU -> half the CUs idle). Direct f32 stores.
__global__ __launch_bounds__(256) void gemm_proj(
    const u16* __restrict__ Oin, const u16* __restrict__ Wp,
    const u16* __restrict__ bp, float* __restrict__ out) {
  __shared__ __align__(16) short As[4096], Bs[4096];   // 16KB
  const int t = threadIdx.x;
  const int lane = t & 63, w = t >> 6, quad = lane >> 4, l16 = lane & 15;
  const int wm = (w >> 1) * 32, wn = (w & 1) * 32;
  const int row4 = t >> 2, chunk = (t & 3) * 8;
  const int m0 = blockIdx.y * 64, n0 = blockIdx.x * 64;
  const u16* Ab = Oin + m0 * CDIM;
  const u16* Wb = Wp + n0 * CDIM;
  f32x4 acc[2][2];
#pragma unroll
  for (int i = 0; i < 2; i++)
#pragma unroll
    for (int j = 0; j < 2; j++) acc[i][j] = 0.f;

  for (int k0 = 0; k0 < CDIM; k0 += 64) {
#pragma unroll
    for (int hh = 0; hh < 2; hh++) {
      const u16* ga = Ab + row4 * CDIM + k0 + hh * 32 + chunk;
      const u16* gb = Wb + row4 * CDIM + k0 + hh * 32 + chunk;
      lds_load16(ga, (char*)As + hh * 4096 + t * 16);
      lds_load16(gb, (char*)Bs + hh * 4096 + t * 16);
    }
    __syncthreads();
#pragma unroll
    for (int hh = 0; hh < 2; hh++) {
      const short* Ah = As + hh * 2048;
      const short* Bh = Bs + hh * 2048;
      short8 af[2], bw[2];
#pragma unroll
      for (int i = 0; i < 2; i++)
        af[i] = *(const short8*)(Ah + (wm + i * 16 + l16) * 32 + quad * 8);
#pragma unroll
      for (int j = 0; j < 2; j++)
        bw[j] = *(const short8*)(Bh + (wn + j * 16 + l16) * 32 + quad * 8);
#pragma unroll
      for (int i = 0; i < 2; i++)
#pragma unroll
        for (int j = 0; j < 2; j++)
          acc[i][j] = mfma16(af[i], bw[j], acc[i][j]);
    }
    __syncthreads();
  }

#pragma unroll
  for (int i = 0; i < 2; i++) {
    int mrow = m0 + wm + i * 16 + quad * 4;
#pragma unroll
    for (int j = 0; j < 2; j++) {
      int n = n0 + wn + j * 16 + l16;
      float bias = bf2f(bp[n]);
#pragma unroll
      for (int r = 0; r < 4; r++)
        out[(mrow + r) * CDIM + n] = acc[i][j][r] + bias;
    }
  }
}

extern "C" void kernel_launch(void* const* d_in, const int* in_sizes, int n_in,
                              void* d_out, int out_size, void* d_ws, size_t ws_size,
                              hipStream_t stream) {
  (void)in_sizes; (void)n_in; (void)out_size;
  const size_t OFF_XQ = 0, OFF_XK = (size_t)MC, OFF_XV = 2ull * MC,
               OFF_Q = 3ull * MC, OFF_K = 4ull * MC, OFF_VT = 5ull * MC,
               OFF_W = 6ull * MC, TOT = OFF_W + 4ull * WSZ + 1024;
  const size_t NEED = 2 * TOT;
  if (ws_size < NEED) return;

  u16* ws = (u16*)d_ws;
  u16 *Xq = ws + OFF_XQ, *Xk = ws + OFF_XK, *Xv = ws + OFF_XV;
  u16 *Qb = ws + OFF_Q, *Kb = ws + OFF_K, *Vt = ws + OFF_VT;
  u16 *Wb = ws + OFF_W;
  u16 *Wqb = Wb, *Wkb = Wb + WSZ, *Wvb = Wb + 2ull * WSZ,
      *Wpb = Wb + 3ull * WSZ, *bpb = Wb + 4ull * WSZ;
  u16* Ob = Xq;

  prep_all<<<PREP_BLKS + CONV_BLKS, 256, 0, stream>>>(
      (const float*)d_in[0], (const float*)d_in[1], (const float*)d_in[2],
      (const float*)d_in[4], (const float*)d_in[5], (const float*)d_in[6],
      (const float*)d_in[7], (const float*)d_in[8], Xq, Xk, Xv, Wb);
  gemm_qkv<<<dim3(6, 64, 3), 256, 0, stream>>>(Xq, Xk, Xv, Wqb, Wkb, Wvb,
                                               Qb, Kb, Vt);
  attn<<<dim3(768), 256, 0, stream>>>(Qb, Kb, Vt, (const float*)d_in[3], Ob);
  gemm_proj<<<dim3(12, 64), 256, 0, stream>>>(Ob, Wpb, bpb, (float*)d_out);
}